// Round 2
// baseline (707.062 us; speedup 1.0000x reference)
//
#include <hip/hip_runtime.h>

#define LN_EPS 1e-5f
#define LOG2E 1.44269504f
#define NHALF_LOG2E (-0.72134752f)

#if __has_builtin(__builtin_amdgcn_exp2f)
#define EXP2F(x) __builtin_amdgcn_exp2f(x)
#else
#define EXP2F(x) __expf((x) * 0.69314718f)
#endif

// Single megakernel: transpose -> wav0 -> ln0 -> wav1 -> ln1 -> wav2 -> ln2+cls.
// Round-1 lesson: hipLaunchCooperativeKernel silently failed (out never written,
// absmax == max|ref|). Replaced with a hand-rolled device-scope barrier.
// Grid = 256 blocks x 512 threads: 1 block/CU ALWAYS co-resident (8 waves/block,
// 48KB LDS) for any VGPR count -> software grid barrier cannot deadlock.
// Barrier: monotone atomicAdd counter (targets k*NBLK, no reset), zeroed per
// launch by a capture-safe hipMemsetAsync. __threadfence + acq/rel agent-scope
// atomics cover cross-XCD L2 non-coherence.

constexpr int NBLK   = 256;
constexpr int TPB    = 512;
constexpr int NWAVES = NBLK * (TPB / 64);   // 2048

// ---------------------------------------------------------------------------
__device__ __forceinline__ void gridbar(int* __restrict__ cnt, int target)
{
    __syncthreads();
    if (threadIdx.x == 0) {
        __threadfence();  // release prior global writes (agent scope)
        __hip_atomic_fetch_add(cnt, 1, __ATOMIC_RELEASE, __HIP_MEMORY_SCOPE_AGENT);
        while (__hip_atomic_load(cnt, __ATOMIC_ACQUIRE, __HIP_MEMORY_SCOPE_AGENT) < target)
            __builtin_amdgcn_s_sleep(2);
        __threadfence();  // acquire side
    }
    __syncthreads();
}

// ---------------------------------------------------------------------------
// Wavelet layer phase. Task = (o, si); wave gw does TPW consecutive tasks.
// Per-wave LDS prep slab: float4 {inv, -t*inv, w, pad} per i.
// Math identical to the verified 7-kernel version.
// ---------------------------------------------------------------------------
template<int KINL, int S>
__device__ __forceinline__ void wav_phase(const float* __restrict__ xin,
        const float* __restrict__ w, const float* __restrict__ t,
        const float* __restrict__ s, float* __restrict__ part,
        float4* __restrict__ myPrep, int lane, int gw)
{
    constexpr int RANGE = KINL / S;      // i-values per task
    constexpr int STEPS = RANGE / 4;
    constexpr int PREPS = RANGE / 64;
    constexpr int NT    = 512 * S;       // total tasks
    constexpr int TPW   = NT / NWAVES;   // tasks per wave (exact)

#pragma unroll
    for (int ti = 0; ti < TPW; ++ti) {
        const int tau = gw * TPW + ti;
        const int o = tau & 511, si = tau >> 9;
        const int ibase = si * RANGE;

        const float* __restrict__ wp = w + (size_t)o * KINL + ibase;
        const float* __restrict__ tp = t + (size_t)o * KINL + ibase;
        const float* __restrict__ sp = s + (size_t)o * KINL + ibase;

        // prep slab is per-wave; within-wave DS ordering is in-order -> no sync
#pragma unroll
        for (int r = 0; r < PREPS; ++r) {
            int il = r * 64 + lane;
            float wv = wp[il], tv = tp[il], sv = sp[il];
            float sig = __builtin_amdgcn_rcpf(1.f + EXP2F(-sv * LOG2E));
            float inv = __builtin_amdgcn_rcpf(fmaf(9.99f, sig, 0.01000001f));
            myPrep[il] = make_float4(inv, -tv * inv, wv, 0.f);
        }

        const int p = lane & 15, g = lane >> 4;
        const float2* __restrict__ xp =
            (const float2*)xin + (size_t)(ibase + g) * 16 + p;

        float acc0 = 0.f, acc1 = 0.f;
#pragma unroll 8
        for (int st = 0; st < STEPS; ++st) {
            float4 pr = myPrep[st * 4 + g];          // one ds_read_b128, broadcast
            float2 xv = xp[(size_t)st * 64];         // 512B contiguous per wave
            float u0 = fmaf(xv.x, pr.x, pr.y);
            float u1 = fmaf(xv.y, pr.x, pr.y);
            float q0 = u0 * u0, q1 = u1 * u1;
            float e0 = EXP2F(q0 * NHALF_LOG2E);
            float e1 = EXP2F(q1 * NHALF_LOG2E);
            float pw0 = fmaf(-pr.z, q0, pr.z);
            float pw1 = fmaf(-pr.z, q1, pr.z);
            acc0 = fmaf(pw0, e0, acc0);
            acc1 = fmaf(pw1, e1, acc1);
        }

        acc0 += __shfl_down(acc0, 32); acc0 += __shfl_down(acc0, 16);
        acc1 += __shfl_down(acc1, 32); acc1 += __shfl_down(acc1, 16);
        if (lane < 16) {
            float2* pp = (float2*)(part + (size_t)si * 16384 + o * 32) + p;
            *pp = make_float2(acc0, acc1);
        }
    }
}

// ---------------------------------------------------------------------------
// silu + LayerNorm phase: one wave per batch row (waves 0..31), lane owns
// o = lane + 64*j for j<8. Writes hT[o][b].
// ---------------------------------------------------------------------------
template<int S>
__device__ __forceinline__ void ln_phase(const float* __restrict__ part,
        const float* __restrict__ gam, const float* __restrict__ bet,
        float* __restrict__ hT, int lane, int gw)
{
    if (gw < 32) {
        const int b = gw;
        float a[8]; float s1 = 0.f, s2 = 0.f;
#pragma unroll
        for (int j = 0; j < 8; ++j) {
            const int o = lane + 64 * j;
            float v = 0.f;
#pragma unroll
            for (int si = 0; si < S; ++si)
                v += part[(size_t)si * 16384 + o * 32 + b];
            float av = v * __builtin_amdgcn_rcpf(1.f + EXP2F(-v * LOG2E));
            a[j] = av; s1 += av; s2 += av * av;
        }
#pragma unroll
        for (int off = 32; off; off >>= 1) {
            s1 += __shfl_xor(s1, off);
            s2 += __shfl_xor(s2, off);
        }
        float m   = s1 * (1.f / 512.f);
        float var = s2 * (1.f / 512.f) - m * m;
        float r   = __builtin_amdgcn_rsqf(var + LN_EPS);
#pragma unroll
        for (int j = 0; j < 8; ++j) {
            const int o = lane + 64 * j;
            hT[o * 32 + b] = (a[j] - m) * r * gam[o] + bet[o];
        }
    }
}

// ---------------------------------------------------------------------------
// Final: silu + LN + classifier. One wave per batch row.
// ---------------------------------------------------------------------------
template<int S>
__device__ __forceinline__ void cls_phase(const float* __restrict__ part,
        const float* __restrict__ gam, const float* __restrict__ bet,
        const float* __restrict__ cw, const float* __restrict__ cb,
        float* __restrict__ out, int lane, int gw)
{
    if (gw < 32) {
        const int b = gw;
        float a[8]; float s1 = 0.f, s2 = 0.f;
#pragma unroll
        for (int j = 0; j < 8; ++j) {
            const int o = lane + 64 * j;
            float v = 0.f;
#pragma unroll
            for (int si = 0; si < S; ++si)
                v += part[(size_t)si * 16384 + o * 32 + b];
            float av = v * __builtin_amdgcn_rcpf(1.f + EXP2F(-v * LOG2E));
            a[j] = av; s1 += av; s2 += av * av;
        }
#pragma unroll
        for (int off = 32; off; off >>= 1) {
            s1 += __shfl_xor(s1, off);
            s2 += __shfl_xor(s2, off);
        }
        float m   = s1 * (1.f / 512.f);
        float var = s2 * (1.f / 512.f) - m * m;
        float r   = __builtin_amdgcn_rsqf(var + LN_EPS);

        float c0 = 0.f, c1 = 0.f, c2 = 0.f, c3 = 0.f, c4 = 0.f;
#pragma unroll
        for (int j = 0; j < 8; ++j) {
            const int o = lane + 64 * j;
            float hl = (a[j] - m) * r * gam[o] + bet[o];
            c0 = fmaf(hl, cw[0 * 512 + o], c0);
            c1 = fmaf(hl, cw[1 * 512 + o], c1);
            c2 = fmaf(hl, cw[2 * 512 + o], c2);
            c3 = fmaf(hl, cw[3 * 512 + o], c3);
            c4 = fmaf(hl, cw[4 * 512 + o], c4);
        }
#pragma unroll
        for (int off = 32; off; off >>= 1) {
            c0 += __shfl_xor(c0, off); c1 += __shfl_xor(c1, off);
            c2 += __shfl_xor(c2, off); c3 += __shfl_xor(c3, off);
            c4 += __shfl_xor(c4, off);
        }
        if (lane == 0) {
            out[b * 5 + 0] = c0 + cb[0];
            out[b * 5 + 1] = c1 + cb[1];
            out[b * 5 + 2] = c2 + cb[2];
            out[b * 5 + 3] = c3 + cb[3];
            out[b * 5 + 4] = c4 + cb[4];
        }
    }
}

// ---------------------------------------------------------------------------
__global__ __launch_bounds__(TPB)
void megakernel(const float* __restrict__ x,
                const float* __restrict__ w0, const float* __restrict__ t0,
                const float* __restrict__ s0, const float* __restrict__ g0,
                const float* __restrict__ b0,
                const float* __restrict__ w1, const float* __restrict__ t1,
                const float* __restrict__ s1, const float* __restrict__ g1,
                const float* __restrict__ b1,
                const float* __restrict__ w2, const float* __restrict__ t2,
                const float* __restrict__ s2, const float* __restrict__ g2,
                const float* __restrict__ b2,
                const float* __restrict__ cw, const float* __restrict__ cb,
                float* __restrict__ out,
                float* __restrict__ xT, float* __restrict__ part,
                float* __restrict__ hT, int* __restrict__ bar)
{
    __shared__ float4 prep[8][384];          // 48 KiB: per-wave prep slab

    const int wave = threadIdx.x >> 6, lane = threadIdx.x & 63;
    const int gw = blockIdx.x * (TPB / 64) + wave;
    float4* myPrep = prep[wave];

    // phase 0: transpose x (32 x 6144) -> xT (6144 x 32)
    for (int idx = blockIdx.x * TPB + threadIdx.x; idx < 6144 * 32; idx += NBLK * TPB)
        xT[idx] = x[(idx & 31) * 6144 + (idx >> 5)];
    gridbar(bar, 1 * NBLK);

    wav_phase<6144, 16>(xT, w0, t0, s0, part, myPrep, lane, gw);   // 8192 tasks, 4/wave
    gridbar(bar, 2 * NBLK);
    ln_phase<16>(part, g0, b0, hT, lane, gw);
    gridbar(bar, 3 * NBLK);

    wav_phase<512, 8>(hT, w1, t1, s1, part, myPrep, lane, gw);     // 4096 tasks, 2/wave
    gridbar(bar, 4 * NBLK);
    ln_phase<8>(part, g1, b1, hT, lane, gw);
    gridbar(bar, 5 * NBLK);

    wav_phase<512, 8>(hT, w2, t2, s2, part, myPrep, lane, gw);
    gridbar(bar, 6 * NBLK);
    cls_phase<8>(part, g2, b2, cw, cb, out, lane, gw);
}

extern "C" void kernel_launch(void* const* d_in, const int* in_sizes, int n_in,
                              void* d_out, int out_size, void* d_ws, size_t ws_size,
                              hipStream_t stream)
{
    const float* x  = (const float*)d_in[0];
    const float* w0 = (const float*)d_in[1];
    const float* t0 = (const float*)d_in[2];
    const float* s0 = (const float*)d_in[3];
    const float* g0 = (const float*)d_in[4];
    const float* b0 = (const float*)d_in[5];
    const float* w1 = (const float*)d_in[6];
    const float* t1 = (const float*)d_in[7];
    const float* s1 = (const float*)d_in[8];
    const float* g1 = (const float*)d_in[9];
    const float* b1 = (const float*)d_in[10];
    const float* w2 = (const float*)d_in[11];
    const float* t2 = (const float*)d_in[12];
    const float* s2 = (const float*)d_in[13];
    const float* g2 = (const float*)d_in[14];
    const float* b2 = (const float*)d_in[15];
    const float* cw = (const float*)d_in[16];
    const float* cb = (const float*)d_in[17];
    float* out = (float*)d_out;

    // ws layout (floats): xT 196608 | part 16*16384 | hT 16384 | barrier
    float* xT   = (float*)d_ws;
    float* part = xT + 196608;
    float* hT   = part + 16 * 16384;
    int*   bar  = (int*)(hT + 16384);        // 64B-aligned (offset 1900544)

    hipMemsetAsync(bar, 0, 64, stream);      // capture-safe barrier reset

    void* args[] = { (void*)&x,
                     (void*)&w0, (void*)&t0, (void*)&s0, (void*)&g0, (void*)&b0,
                     (void*)&w1, (void*)&t1, (void*)&s1, (void*)&g1, (void*)&b1,
                     (void*)&w2, (void*)&t2, (void*)&s2, (void*)&g2, (void*)&b2,
                     (void*)&cw, (void*)&cb, (void*)&out,
                     (void*)&xT, (void*)&part, (void*)&hT, (void*)&bar };

    hipLaunchKernel((const void*)megakernel, dim3(NBLK), dim3(TPB),
                    args, 0, stream);
}

// Round 3
// 255.102 us; speedup vs baseline: 2.7717x; 2.7717x over previous
//
#include <hip/hip_runtime.h>

#define LN_EPS 1e-5f
#define LOG2E 1.44269504f
#define NHALF_LOG2E (-0.72134752f)

#if __has_builtin(__builtin_amdgcn_exp2f)
#define EXP2F(x) __builtin_amdgcn_exp2f(x)
#else
#define EXP2F(x) __expf((x) * 0.69314718f)
#endif

// Megakernel: transpose -> wav0 -> ln0 -> wav1 -> ln1 -> wav2 -> ln2+cls.
// Round-2 lesson: ACQUIRE atomic polls emit a cache-invalidate per iteration;
// 255 spinning blocks = L2-invalidation storm -> 615us with VALUBusy 2.9%.
// Fix: relaxed polls + one release fence before arrive and one acquire fence
// after exit (fence-to-fence sync through the counter). LN/cls phases use the
// proven 32-blocks x 512-threads shape (8x more parallel than waves 0..31).
// Grid = 256 blocks x 512 threads: 1 block/CU ALWAYS co-resident -> no deadlock.

constexpr int NBLK   = 256;
constexpr int TPB    = 512;
constexpr int NWAVES = NBLK * (TPB / 64);   // 2048

// ---------------------------------------------------------------------------
__device__ __forceinline__ void gridbar(int* __restrict__ cnt, int target)
{
    __syncthreads();
    if (threadIdx.x == 0) {
        __threadfence();  // release: write back this XCD's dirty lines (once)
        __hip_atomic_fetch_add(cnt, 1, __ATOMIC_RELAXED, __HIP_MEMORY_SCOPE_AGENT);
        while (__hip_atomic_load(cnt, __ATOMIC_RELAXED, __HIP_MEMORY_SCOPE_AGENT) < target)
            __builtin_amdgcn_s_sleep(8);   // relaxed poll: NO per-iter invalidate
        __threadfence();  // acquire: invalidate stale lines (once)
    }
    __syncthreads();
}

// ---------------------------------------------------------------------------
// Wavelet layer phase. Task = (o, si); wave gw does TPW consecutive tasks.
// Per-wave LDS prep slab: float4 {inv, -t*inv, w, pad} per i.
// Math identical to the verified 7-kernel version.
// ---------------------------------------------------------------------------
template<int KINL, int S>
__device__ __forceinline__ void wav_phase(const float* __restrict__ xin,
        const float* __restrict__ w, const float* __restrict__ t,
        const float* __restrict__ s, float* __restrict__ part,
        float4* __restrict__ myPrep, int lane, int gw)
{
    constexpr int RANGE = KINL / S;      // i-values per task
    constexpr int STEPS = RANGE / 4;
    constexpr int PREPS = RANGE / 64;
    constexpr int NT    = 512 * S;       // total tasks
    constexpr int TPW   = NT / NWAVES;   // tasks per wave (exact)

#pragma unroll
    for (int ti = 0; ti < TPW; ++ti) {
        const int tau = gw * TPW + ti;
        const int o = tau & 511, si = tau >> 9;
        const int ibase = si * RANGE;

        const float* __restrict__ wp = w + (size_t)o * KINL + ibase;
        const float* __restrict__ tp = t + (size_t)o * KINL + ibase;
        const float* __restrict__ sp = s + (size_t)o * KINL + ibase;

        // prep slab is per-wave; within-wave DS ordering is in-order -> no sync
#pragma unroll
        for (int r = 0; r < PREPS; ++r) {
            int il = r * 64 + lane;
            float wv = wp[il], tv = tp[il], sv = sp[il];
            float sig = __builtin_amdgcn_rcpf(1.f + EXP2F(-sv * LOG2E));
            float inv = __builtin_amdgcn_rcpf(fmaf(9.99f, sig, 0.01000001f));
            myPrep[il] = make_float4(inv, -tv * inv, wv, 0.f);
        }

        const int p = lane & 15, g = lane >> 4;
        const float2* __restrict__ xp =
            (const float2*)xin + (size_t)(ibase + g) * 16 + p;

        float acc0 = 0.f, acc1 = 0.f;
#pragma unroll 8
        for (int st = 0; st < STEPS; ++st) {
            float4 pr = myPrep[st * 4 + g];          // one ds_read_b128, broadcast
            float2 xv = xp[(size_t)st * 64];         // 512B contiguous per wave
            float u0 = fmaf(xv.x, pr.x, pr.y);
            float u1 = fmaf(xv.y, pr.x, pr.y);
            float q0 = u0 * u0, q1 = u1 * u1;
            float e0 = EXP2F(q0 * NHALF_LOG2E);
            float e1 = EXP2F(q1 * NHALF_LOG2E);
            float pw0 = fmaf(-pr.z, q0, pr.z);
            float pw1 = fmaf(-pr.z, q1, pr.z);
            acc0 = fmaf(pw0, e0, acc0);
            acc1 = fmaf(pw1, e1, acc1);
        }

        acc0 += __shfl_down(acc0, 32); acc0 += __shfl_down(acc0, 16);
        acc1 += __shfl_down(acc1, 32); acc1 += __shfl_down(acc1, 16);
        if (lane < 16) {
            float2* pp = (float2*)(part + (size_t)si * 16384 + o * 32) + p;
            *pp = make_float2(acc0, acc1);
        }
    }
}

// ---------------------------------------------------------------------------
// silu + LayerNorm phase: block b (<32) = batch row, tid = o. Writes hT[o][b].
// Bit-identical to the verified standalone silu_ln kernel.
// ---------------------------------------------------------------------------
template<int S>
__device__ __forceinline__ void ln_phase(const float* __restrict__ part,
        const float* __restrict__ gam, const float* __restrict__ bet,
        float* __restrict__ hT, float* __restrict__ r1, float* __restrict__ r2)
{
    if (blockIdx.x < 32) {
        const int b = blockIdx.x, tid = threadIdx.x;
        float v = 0.f;
#pragma unroll
        for (int si = 0; si < S; ++si) v += part[(size_t)si * 16384 + tid * 32 + b];
        float a = v * __builtin_amdgcn_rcpf(1.f + EXP2F(-v * LOG2E));  // silu

        float s1 = a, s2 = a * a;
#pragma unroll
        for (int off = 32; off; off >>= 1) {
            s1 += __shfl_down(s1, off);
            s2 += __shfl_down(s2, off);
        }
        const int lane = tid & 63, wid = tid >> 6;
        if (lane == 0) { r1[wid] = s1; r2[wid] = s2; }
        __syncthreads();
        float t1 = 0.f, t2 = 0.f;
#pragma unroll
        for (int k = 0; k < 8; ++k) { t1 += r1[k]; t2 += r2[k]; }
        float m   = t1 * (1.f / 512.f);
        float var = t2 * (1.f / 512.f) - m * m;
        float r   = __builtin_amdgcn_rsqf(var + LN_EPS);
        hT[tid * 32 + b] = (a - m) * r * gam[tid] + bet[tid];
    }
}

// ---------------------------------------------------------------------------
// Final: silu + LN + classifier, block b (<32) = batch row, tid = o.
// Bit-identical to the verified standalone silu_ln_cls kernel.
// ---------------------------------------------------------------------------
template<int S>
__device__ __forceinline__ void cls_phase(const float* __restrict__ part,
        const float* __restrict__ gam, const float* __restrict__ bet,
        const float* __restrict__ cw, const float* __restrict__ cb,
        float* __restrict__ out, float* __restrict__ r1, float* __restrict__ r2,
        float (* __restrict__ cr)[8])
{
    if (blockIdx.x < 32) {
        const int b = blockIdx.x, tid = threadIdx.x;
        float v = 0.f;
#pragma unroll
        for (int si = 0; si < S; ++si) v += part[(size_t)si * 16384 + tid * 32 + b];
        float a = v * __builtin_amdgcn_rcpf(1.f + EXP2F(-v * LOG2E));

        float s1 = a, s2 = a * a;
#pragma unroll
        for (int off = 32; off; off >>= 1) {
            s1 += __shfl_down(s1, off);
            s2 += __shfl_down(s2, off);
        }
        const int lane = tid & 63, wid = tid >> 6;
        if (lane == 0) { r1[wid] = s1; r2[wid] = s2; }
        __syncthreads();
        float t1 = 0.f, t2 = 0.f;
#pragma unroll
        for (int k = 0; k < 8; ++k) { t1 += r1[k]; t2 += r2[k]; }
        float m   = t1 * (1.f / 512.f);
        float var = t2 * (1.f / 512.f) - m * m;
        float r   = __builtin_amdgcn_rsqf(var + LN_EPS);
        float hl  = (a - m) * r * gam[tid] + bet[tid];

#pragma unroll
        for (int c = 0; c < 5; ++c) {
            float pv = hl * cw[c * 512 + tid];
#pragma unroll
            for (int off = 32; off; off >>= 1) pv += __shfl_down(pv, off);
            if (lane == 0) cr[c][wid] = pv;
        }
        __syncthreads();
        if (tid < 5) {
            float sum = 0.f;
#pragma unroll
            for (int k = 0; k < 8; ++k) sum += cr[tid][k];
            out[b * 5 + tid] = sum + cb[tid];
        }
    }
}

// ---------------------------------------------------------------------------
__global__ __launch_bounds__(TPB)
void megakernel(const float* __restrict__ x,
                const float* __restrict__ w0, const float* __restrict__ t0,
                const float* __restrict__ s0, const float* __restrict__ g0,
                const float* __restrict__ b0,
                const float* __restrict__ w1, const float* __restrict__ t1,
                const float* __restrict__ s1, const float* __restrict__ g1,
                const float* __restrict__ b1,
                const float* __restrict__ w2, const float* __restrict__ t2,
                const float* __restrict__ s2, const float* __restrict__ g2,
                const float* __restrict__ b2,
                const float* __restrict__ cw, const float* __restrict__ cb,
                float* __restrict__ out,
                float* __restrict__ xT, float* __restrict__ part,
                float* __restrict__ hT, int* __restrict__ bar)
{
    __shared__ float4 prep[8][384];          // 48 KiB: per-wave prep slab
    __shared__ float r1[8], r2[8], cr[5][8]; // LN/cls reduction scratch

    const int wave = threadIdx.x >> 6, lane = threadIdx.x & 63;
    const int gw = blockIdx.x * (TPB / 64) + wave;
    float4* myPrep = prep[wave];

    // phase 0: transpose x (32 x 6144) -> xT (6144 x 32)
    for (int idx = blockIdx.x * TPB + threadIdx.x; idx < 6144 * 32; idx += NBLK * TPB)
        xT[idx] = x[(idx & 31) * 6144 + (idx >> 5)];
    gridbar(bar, 1 * NBLK);

    wav_phase<6144, 16>(xT, w0, t0, s0, part, myPrep, lane, gw);   // 8192 tasks, 4/wave
    gridbar(bar, 2 * NBLK);
    ln_phase<16>(part, g0, b0, hT, r1, r2);
    gridbar(bar, 3 * NBLK);

    wav_phase<512, 8>(hT, w1, t1, s1, part, myPrep, lane, gw);     // 4096 tasks, 2/wave
    gridbar(bar, 4 * NBLK);
    ln_phase<8>(part, g1, b1, hT, r1, r2);
    gridbar(bar, 5 * NBLK);

    wav_phase<512, 8>(hT, w2, t2, s2, part, myPrep, lane, gw);
    gridbar(bar, 6 * NBLK);
    cls_phase<8>(part, g2, b2, cw, cb, out, r1, r2, cr);
}

extern "C" void kernel_launch(void* const* d_in, const int* in_sizes, int n_in,
                              void* d_out, int out_size, void* d_ws, size_t ws_size,
                              hipStream_t stream)
{
    const float* x  = (const float*)d_in[0];
    const float* w0 = (const float*)d_in[1];
    const float* t0 = (const float*)d_in[2];
    const float* s0 = (const float*)d_in[3];
    const float* g0 = (const float*)d_in[4];
    const float* b0 = (const float*)d_in[5];
    const float* w1 = (const float*)d_in[6];
    const float* t1 = (const float*)d_in[7];
    const float* s1 = (const float*)d_in[8];
    const float* g1 = (const float*)d_in[9];
    const float* b1 = (const float*)d_in[10];
    const float* w2 = (const float*)d_in[11];
    const float* t2 = (const float*)d_in[12];
    const float* s2 = (const float*)d_in[13];
    const float* g2 = (const float*)d_in[14];
    const float* b2 = (const float*)d_in[15];
    const float* cw = (const float*)d_in[16];
    const float* cb = (const float*)d_in[17];
    float* out = (float*)d_out;

    // ws layout (floats): xT 196608 | part 16*16384 | hT 16384 | barrier
    float* xT   = (float*)d_ws;
    float* part = xT + 196608;
    float* hT   = part + 16 * 16384;
    int*   bar  = (int*)(hT + 16384);        // 64B-aligned (offset 1900544)

    hipMemsetAsync(bar, 0, 64, stream);      // capture-safe barrier reset

    void* args[] = { (void*)&x,
                     (void*)&w0, (void*)&t0, (void*)&s0, (void*)&g0, (void*)&b0,
                     (void*)&w1, (void*)&t1, (void*)&s1, (void*)&g1, (void*)&b1,
                     (void*)&w2, (void*)&t2, (void*)&s2, (void*)&g2, (void*)&b2,
                     (void*)&cw, (void*)&cb, (void*)&out,
                     (void*)&xT, (void*)&part, (void*)&hT, (void*)&bar };

    hipLaunchKernel((const void*)megakernel, dim3(NBLK), dim3(TPB),
                    args, 0, stream);
}

// Round 4
// 233.916 us; speedup vs baseline: 3.0227x; 1.0906x over previous
//
#include <hip/hip_runtime.h>

#define LN_EPS 1e-5f
#define LOG2E 1.44269504f
#define NHALF_LOG2E (-0.72134752f)

#if __has_builtin(__builtin_amdgcn_exp2f)
#define EXP2F(x) __builtin_amdgcn_exp2f(x)
#else
#define EXP2F(x) __expf((x) * 0.69314718f)
#endif

// Megakernel: transpose -> wav0 -> ln0 -> wav1 -> ln1 -> wav2 -> ln2+cls.
// Round-3 lesson: flat barrier (256 adds + 256 pollers on ONE line) serializes
// at the coherence point -> ~25us/barrier, kernel 166us with VALUBusy 11%.
// Fix: hierarchical barrier. 8 group-arrival counters (32 blocks each, own
// cache lines; the add RETURN VALUE identifies the group-last -> zero polling
// at this level), group-lasts bump a global counter (8 ops), global-last
// broadcasts a phase stamp to 8 per-group release flags; blocks poll ONLY
// their group flag (<=32 pollers/line, s_sleep(32) ~2us period).
// Monotone epochs, no reset. Fences form a B->L->F->P release chain.
// Grid = 256 blocks x 512 threads: 1 block/CU ALWAYS co-resident -> no deadlock.

constexpr int NBLK   = 256;
constexpr int TPB    = 512;
constexpr int NWAVES = NBLK * (TPB / 64);   // 2048
constexpr int NGRP   = 8;
constexpr int GRP    = NBLK / NGRP;         // 32

// barrier memory layout (ints, 32-int = 128B stride per slot):
// [0..255]   grpArr[g] at g*32
// [256..511] grpRel[g] at 256 + g*32
// [512]      gArr
// ---------------------------------------------------------------------------
__device__ __forceinline__ void gridbar(int* __restrict__ bar, int k)
{
    __syncthreads();
    if (threadIdx.x == 0) {
        const int g = blockIdx.x >> 5;          // group of 32 blocks
        int* grpArr = bar + g * 32;
        int* grpRel = bar + 256 + g * 32;
        int* gArr   = bar + 512;

        __threadfence();  // release my phase's global writes
        int old = __hip_atomic_fetch_add(grpArr, 1, __ATOMIC_RELAXED,
                                         __HIP_MEMORY_SCOPE_AGENT);
        if (old == k * GRP - 1) {               // last arriver in group
            __threadfence();                    // acquire others' / release mine
            int o2 = __hip_atomic_fetch_add(gArr, 1, __ATOMIC_RELAXED,
                                            __HIP_MEMORY_SCOPE_AGENT);
            if (o2 == k * NGRP - 1) {           // last group: broadcast release
                __threadfence();
#pragma unroll
                for (int j = 0; j < NGRP; ++j)
                    __hip_atomic_store(bar + 256 + j * 32, k, __ATOMIC_RELAXED,
                                       __HIP_MEMORY_SCOPE_AGENT);
            }
        }
        while (__hip_atomic_load(grpRel, __ATOMIC_RELAXED,
                                 __HIP_MEMORY_SCOPE_AGENT) < k)
            __builtin_amdgcn_s_sleep(32);       // ~2us poll period, no invalidate
        __threadfence();  // acquire side
    }
    __syncthreads();
}

// ---------------------------------------------------------------------------
// Wavelet layer phase. Task = (o, si); wave gw does TPW consecutive tasks.
// Per-wave LDS prep slab: float4 {inv, -t*inv, w, pad} per i.
// Math identical to the verified 7-kernel version.
// ---------------------------------------------------------------------------
template<int KINL, int S>
__device__ __forceinline__ void wav_phase(const float* __restrict__ xin,
        const float* __restrict__ w, const float* __restrict__ t,
        const float* __restrict__ s, float* __restrict__ part,
        float4* __restrict__ myPrep, int lane, int gw)
{
    constexpr int RANGE = KINL / S;      // i-values per task
    constexpr int STEPS = RANGE / 4;
    constexpr int PREPS = RANGE / 64;
    constexpr int NT    = 512 * S;       // total tasks
    constexpr int TPW   = NT / NWAVES;   // tasks per wave (exact)

#pragma unroll
    for (int ti = 0; ti < TPW; ++ti) {
        const int tau = gw * TPW + ti;
        const int o = tau & 511, si = tau >> 9;
        const int ibase = si * RANGE;

        const float* __restrict__ wp = w + (size_t)o * KINL + ibase;
        const float* __restrict__ tp = t + (size_t)o * KINL + ibase;
        const float* __restrict__ sp = s + (size_t)o * KINL + ibase;

        // prep slab is per-wave; within-wave DS ordering is in-order -> no sync
#pragma unroll
        for (int r = 0; r < PREPS; ++r) {
            int il = r * 64 + lane;
            float wv = wp[il], tv = tp[il], sv = sp[il];
            float sig = __builtin_amdgcn_rcpf(1.f + EXP2F(-sv * LOG2E));
            float inv = __builtin_amdgcn_rcpf(fmaf(9.99f, sig, 0.01000001f));
            myPrep[il] = make_float4(inv, -tv * inv, wv, 0.f);
        }

        const int p = lane & 15, g = lane >> 4;
        const float2* __restrict__ xp =
            (const float2*)xin + (size_t)(ibase + g) * 16 + p;

        float acc0 = 0.f, acc1 = 0.f;
#pragma unroll 8
        for (int st = 0; st < STEPS; ++st) {
            float4 pr = myPrep[st * 4 + g];          // one ds_read_b128, broadcast
            float2 xv = xp[(size_t)st * 64];         // 512B contiguous per wave
            float u0 = fmaf(xv.x, pr.x, pr.y);
            float u1 = fmaf(xv.y, pr.x, pr.y);
            float q0 = u0 * u0, q1 = u1 * u1;
            float e0 = EXP2F(q0 * NHALF_LOG2E);
            float e1 = EXP2F(q1 * NHALF_LOG2E);
            float pw0 = fmaf(-pr.z, q0, pr.z);
            float pw1 = fmaf(-pr.z, q1, pr.z);
            acc0 = fmaf(pw0, e0, acc0);
            acc1 = fmaf(pw1, e1, acc1);
        }

        acc0 += __shfl_down(acc0, 32); acc0 += __shfl_down(acc0, 16);
        acc1 += __shfl_down(acc1, 32); acc1 += __shfl_down(acc1, 16);
        if (lane < 16) {
            float2* pp = (float2*)(part + (size_t)si * 16384 + o * 32) + p;
            *pp = make_float2(acc0, acc1);
        }
    }
}

// ---------------------------------------------------------------------------
// silu + LayerNorm phase: block b (<32) = batch row, tid = o. Writes hT[o][b].
// ---------------------------------------------------------------------------
template<int S>
__device__ __forceinline__ void ln_phase(const float* __restrict__ part,
        const float* __restrict__ gam, const float* __restrict__ bet,
        float* __restrict__ hT, float* __restrict__ r1, float* __restrict__ r2)
{
    if (blockIdx.x < 32) {
        const int b = blockIdx.x, tid = threadIdx.x;
        float v = 0.f;
#pragma unroll
        for (int si = 0; si < S; ++si) v += part[(size_t)si * 16384 + tid * 32 + b];
        float a = v * __builtin_amdgcn_rcpf(1.f + EXP2F(-v * LOG2E));  // silu

        float s1 = a, s2 = a * a;
#pragma unroll
        for (int off = 32; off; off >>= 1) {
            s1 += __shfl_down(s1, off);
            s2 += __shfl_down(s2, off);
        }
        const int lane = tid & 63, wid = tid >> 6;
        if (lane == 0) { r1[wid] = s1; r2[wid] = s2; }
        __syncthreads();
        float t1 = 0.f, t2 = 0.f;
#pragma unroll
        for (int k = 0; k < 8; ++k) { t1 += r1[k]; t2 += r2[k]; }
        float m   = t1 * (1.f / 512.f);
        float var = t2 * (1.f / 512.f) - m * m;
        float r   = __builtin_amdgcn_rsqf(var + LN_EPS);
        hT[tid * 32 + b] = (a - m) * r * gam[tid] + bet[tid];
    }
}

// ---------------------------------------------------------------------------
// Final: silu + LN + classifier, block b (<32) = batch row, tid = o.
// ---------------------------------------------------------------------------
template<int S>
__device__ __forceinline__ void cls_phase(const float* __restrict__ part,
        const float* __restrict__ gam, const float* __restrict__ bet,
        const float* __restrict__ cw, const float* __restrict__ cb,
        float* __restrict__ out, float* __restrict__ r1, float* __restrict__ r2,
        float (* __restrict__ cr)[8])
{
    if (blockIdx.x < 32) {
        const int b = blockIdx.x, tid = threadIdx.x;
        float v = 0.f;
#pragma unroll
        for (int si = 0; si < S; ++si) v += part[(size_t)si * 16384 + tid * 32 + b];
        float a = v * __builtin_amdgcn_rcpf(1.f + EXP2F(-v * LOG2E));

        float s1 = a, s2 = a * a;
#pragma unroll
        for (int off = 32; off; off >>= 1) {
            s1 += __shfl_down(s1, off);
            s2 += __shfl_down(s2, off);
        }
        const int lane = tid & 63, wid = tid >> 6;
        if (lane == 0) { r1[wid] = s1; r2[wid] = s2; }
        __syncthreads();
        float t1 = 0.f, t2 = 0.f;
#pragma unroll
        for (int k = 0; k < 8; ++k) { t1 += r1[k]; t2 += r2[k]; }
        float m   = t1 * (1.f / 512.f);
        float var = t2 * (1.f / 512.f) - m * m;
        float r   = __builtin_amdgcn_rsqf(var + LN_EPS);
        float hl  = (a - m) * r * gam[tid] + bet[tid];

#pragma unroll
        for (int c = 0; c < 5; ++c) {
            float pv = hl * cw[c * 512 + tid];
#pragma unroll
            for (int off = 32; off; off >>= 1) pv += __shfl_down(pv, off);
            if (lane == 0) cr[c][wid] = pv;
        }
        __syncthreads();
        if (tid < 5) {
            float sum = 0.f;
#pragma unroll
            for (int k = 0; k < 8; ++k) sum += cr[tid][k];
            out[b * 5 + tid] = sum + cb[tid];
        }
    }
}

// ---------------------------------------------------------------------------
__global__ __launch_bounds__(TPB)
void megakernel(const float* __restrict__ x,
                const float* __restrict__ w0, const float* __restrict__ t0,
                const float* __restrict__ s0, const float* __restrict__ g0,
                const float* __restrict__ b0,
                const float* __restrict__ w1, const float* __restrict__ t1,
                const float* __restrict__ s1, const float* __restrict__ g1,
                const float* __restrict__ b1,
                const float* __restrict__ w2, const float* __restrict__ t2,
                const float* __restrict__ s2, const float* __restrict__ g2,
                const float* __restrict__ b2,
                const float* __restrict__ cw, const float* __restrict__ cb,
                float* __restrict__ out,
                float* __restrict__ xT, float* __restrict__ part,
                float* __restrict__ hT, int* __restrict__ bar)
{
    __shared__ float4 prep[8][384];          // 48 KiB: per-wave prep slab
    __shared__ float r1[8], r2[8], cr[5][8]; // LN/cls reduction scratch

    const int wave = threadIdx.x >> 6, lane = threadIdx.x & 63;
    const int gw = blockIdx.x * (TPB / 64) + wave;
    float4* myPrep = prep[wave];

    // phase 0: transpose x (32 x 6144) -> xT (6144 x 32)
    for (int idx = blockIdx.x * TPB + threadIdx.x; idx < 6144 * 32; idx += NBLK * TPB)
        xT[idx] = x[(idx & 31) * 6144 + (idx >> 5)];
    gridbar(bar, 1);

    wav_phase<6144, 16>(xT, w0, t0, s0, part, myPrep, lane, gw);   // 8192 tasks, 4/wave
    gridbar(bar, 2);
    ln_phase<16>(part, g0, b0, hT, r1, r2);
    gridbar(bar, 3);

    wav_phase<512, 8>(hT, w1, t1, s1, part, myPrep, lane, gw);     // 4096 tasks, 2/wave
    gridbar(bar, 4);
    ln_phase<8>(part, g1, b1, hT, r1, r2);
    gridbar(bar, 5);

    wav_phase<512, 8>(hT, w2, t2, s2, part, myPrep, lane, gw);
    gridbar(bar, 6);
    cls_phase<8>(part, g2, b2, cw, cb, out, r1, r2, cr);
}

extern "C" void kernel_launch(void* const* d_in, const int* in_sizes, int n_in,
                              void* d_out, int out_size, void* d_ws, size_t ws_size,
                              hipStream_t stream)
{
    const float* x  = (const float*)d_in[0];
    const float* w0 = (const float*)d_in[1];
    const float* t0 = (const float*)d_in[2];
    const float* s0 = (const float*)d_in[3];
    const float* g0 = (const float*)d_in[4];
    const float* b0 = (const float*)d_in[5];
    const float* w1 = (const float*)d_in[6];
    const float* t1 = (const float*)d_in[7];
    const float* s1 = (const float*)d_in[8];
    const float* g1 = (const float*)d_in[9];
    const float* b1 = (const float*)d_in[10];
    const float* w2 = (const float*)d_in[11];
    const float* t2 = (const float*)d_in[12];
    const float* s2 = (const float*)d_in[13];
    const float* g2 = (const float*)d_in[14];
    const float* b2 = (const float*)d_in[15];
    const float* cw = (const float*)d_in[16];
    const float* cb = (const float*)d_in[17];
    float* out = (float*)d_out;

    // ws layout (floats): xT 196608 | part 16*16384 | hT 16384 | barrier (4KB)
    float* xT   = (float*)d_ws;
    float* part = xT + 196608;
    float* hT   = part + 16 * 16384;
    int*   bar  = (int*)(hT + 16384);        // 128B-strided slots, ~2.1KB used

    hipMemsetAsync(bar, 0, 4096, stream);    // capture-safe barrier reset

    void* args[] = { (void*)&x,
                     (void*)&w0, (void*)&t0, (void*)&s0, (void*)&g0, (void*)&b0,
                     (void*)&w1, (void*)&t1, (void*)&s1, (void*)&g1, (void*)&b1,
                     (void*)&w2, (void*)&t2, (void*)&s2, (void*)&g2, (void*)&b2,
                     (void*)&cw, (void*)&cb, (void*)&out,
                     (void*)&xT, (void*)&part, (void*)&hT, (void*)&bar };

    hipLaunchKernel((const void*)megakernel, dim3(NBLK), dim3(TPB),
                    args, 0, stream);
}